// Round 11
// baseline (375.611 us; speedup 1.0000x reference)
//
#include <hip/hip_runtime.h>
#include <hip/hip_bf16.h>
#include <stdint.h>

typedef __attribute__((ext_vector_type(8))) short bf16x8;
typedef __attribute__((ext_vector_type(4))) float f32x4;

#define PH 130
#define NT 36          // K tiles: 9 taps x 256 ci / BK=64

__device__ __forceinline__ short f2bf(float f) {
  uint32_t u = __builtin_bit_cast(uint32_t, f);
  u = (u + 0x7FFFu + ((u >> 16) & 1u)) >> 16;
  return (short)u;
}

__device__ __forceinline__ uint32_t pack2bf(float lo, float hi) {
  return ((uint32_t)(uint16_t)f2bf(hi) << 16) | (uint16_t)f2bf(lo);
}

__device__ __forceinline__ void gload16(const void* g, void* l) {
  __builtin_amdgcn_global_load_lds(
      (const __attribute__((address_space(1))) void*)g,
      (__attribute__((address_space(3))) void*)l, 16, 0, 0);
}

// ---------------------------------------------------------------------------
// Repack W [256co][256ci][3][3] f32 -> A [co][tap*256+ci] bf16 (tap-major K)
// ---------------------------------------------------------------------------
__global__ void wpack(const float* __restrict__ W, short* __restrict__ A) {
  int tid = blockIdx.x * 256 + threadIdx.x;
  if (tid >= 256 * 2304) return;
  int co = tid / 2304;
  int r  = tid - co * 2304;
  int tap = r >> 8, ci = r & 255;
  A[tid] = f2bf(W[((size_t)(co * 256 + ci)) * 9 + tap]);
}

// ---------------------------------------------------------------------------
// FIR upsample v3: one block per output-row PAIR (p=2t,2t+1), sharing 3
// x-rows (t-1,t,t+1). Row-fold in registers at load; col pass per pair.
// hT[b][p'][q'][ci] bf16, p',q' in [0,130), interior = h[p'-1][q'-1].
// ---------------------------------------------------------------------------
__global__ void fir_up(const float* __restrict__ x, short* __restrict__ hT) {
  const int bt = blockIdx.x;
  const int b = bt / 65, t = bt - b * 65;
  const int ci0 = blockIdx.y << 6;
  const int tid = threadIdx.x;

  if (t == 64) {                           // pad rows pp=0 and pp=129
    short* r0 = hT + ((size_t)(b * PH + 0) * PH) * 256 + ci0;
    short* r1 = hT + ((size_t)(b * PH + 129) * PH) * 256 + ci0;
    for (int idx = tid; idx < PH * 32; idx += 256) {
      int qp = idx >> 5, c2 = (idx & 31) * 2;
      *(uint32_t*)&r0[(size_t)qp * 256 + c2] = 0u;
      *(uint32_t*)&r1[(size_t)qp * 256 + c2] = 0u;
    }
    return;
  }

  __shared__ float F[2][64][65];           // folded rows [pair r][j][ci] (+1 pad)
#pragma unroll
  for (int it = 0; it < 4; ++it) {
    int idx = it * 256 + tid;              // ci = idx>>4, j-quad = idx&15
    int ci = idx >> 4, jq = idx & 15;
    const float* base = &x[((size_t)(b * 256 + ci0 + ci) * 64) * 64 + jq * 4];
    f32x4 vm = {0.f, 0.f, 0.f, 0.f}, vp = {0.f, 0.f, 0.f, 0.f};
    f32x4 v0 = *(const f32x4*)(base + (size_t)t * 64);
    if (t >= 1)  vm = *(const f32x4*)(base + (size_t)(t - 1) * 64);
    if (t <= 62) vp = *(const f32x4*)(base + (size_t)(t + 1) * 64);
#pragma unroll
    for (int e = 0; e < 4; ++e) {
      F[0][jq * 4 + e][ci] = 0.25f * vm[e] + 0.75f * v0[e];
      F[1][jq * 4 + e][ci] = 0.75f * v0[e] + 0.25f * vp[e];
    }
  }
  __syncthreads();

  const int c2 = (tid & 31) * 2;
  const int qg = tid >> 5;
#pragma unroll
  for (int r = 0; r < 2; ++r) {
    short* outrow = hT + ((size_t)(b * PH + (2 * t + 1 + r)) * PH) * 256 + ci0;
    for (int qp = qg; qp < PH; qp += 8) {
      uint32_t out = 0u;
      if (qp >= 1 && qp <= 128) {
        int q = qp - 1;
        int par = q & 1;
        int jb = (q >> 1) - 1 + par;
        float wc0 = par ? 0.75f : 0.25f;
        float wc1 = par ? 0.25f : 0.75f;
        float v00 = 0.f, v01 = 0.f, v10 = 0.f, v11 = 0.f;
        if (jb >= 0)     { v00 = F[r][jb][c2];     v01 = F[r][jb][c2 + 1]; }
        if (jb + 1 < 64) { v10 = F[r][jb + 1][c2]; v11 = F[r][jb + 1][c2 + 1]; }
        out = pack2bf(wc0 * v00 + wc1 * v10, wc0 * v01 + wc1 * v11);
      }
      *(uint32_t*)&outrow[(size_t)qp * 256 + c2] = out;
    }
  }
}

// ---------------------------------------------------------------------------
// Implicit GEMM, 2-blocks/CU occupancy variant:
// BM=128 spatial (one (b,p) row) x BN=128 co, BK=64, 8 waves (2M x 4N),
// wave tile 64q x 32co (acc 4x2 f32x4 = 32 VGPR). LDS 80KB: A ring-3 48KB +
// B dbuf 32KB -> 2 blocks/CU (16 waves/CU). One barrier + one counted
// vmcnt(2) per K-tile (in-flight oldest-first: A(t+1),B(t+1),A(t+2); never 0
// mid-loop). Swizzle phys = L ^ (((L>>7)&7)<<4) both sides (rule 21).
// ---------------------------------------------------------------------------
__global__ __launch_bounds__(512, 4) void conv3x3_gemm(
    const short* __restrict__ hT, const short* __restrict__ Wp,
    const float* __restrict__ bias, float* __restrict__ y) {
  __shared__ short ldsA[3][8192];          // 3 x 16KB [128 rows][64 k]
  __shared__ short ldsB[2][8192];          // 2 x 16KB
  const int tid = threadIdx.x;
  const int lane = tid & 63, w = tid >> 6;
  const int wm = w >> 2, wn = w & 3;       // 2 M-halves x 4 N-quarters

  const int bid = blockIdx.x;
  const int tau = (bid & 7) * 512 + (bid >> 3);  // XCD swizzle, 4096%8==0
  const int mt = tau >> 1, nh = tau & 1;         // M-tile, N-half
  const int b = mt >> 7, p = mt & 127;

  // --- per-lane staging geometry; rule 21 pre-swizzle ---
  const short* srcA[2];
  const short* srcB[2];
#pragma unroll
  for (int i = 0; i < 2; ++i) {
    int o = i * 8192 + w * 1024 + lane * 16;
    int L = o ^ (((o >> 7) & 7) << 4);
    int row = L >> 7, kk = (L & 127) >> 1;       // row in [0,128)
    srcA[i] = hT + ((size_t)((b * PH + p) * PH + row)) * 256 + kk;
    srcB[i] = Wp + (size_t)(nh * 128 + row) * 2304 + kk;
  }

  auto offA = [&](int t) {
    int tap = t >> 2, ci0 = (t & 3) << 6;
    int dm = (tap >= 6) ? 2 : (tap >= 3) ? 1 : 0;
    int dn = tap - 3 * dm;
    return (dm * PH + dn) * 256 + ci0;
  };
  auto offB = [&](int t) { return (t >> 2) * 256 + ((t & 3) << 6); };

  auto stageA = [&](int t) {               // full 16KB tile = 2 issues
    int o = offA(t);
    short* dst = &ldsA[t % 3][0];
#pragma unroll
    for (int i = 0; i < 2; ++i)
      gload16(srcA[i] + o, dst + i * 4096 + w * 512);
  };
  auto stageB = [&](int t) {
    int o = offB(t);
    short* dst = &ldsB[t & 1][0];
#pragma unroll
    for (int i = 0; i < 2; ++i)
      gload16(srcB[i] + o, dst + i * 4096 + w * 512);
  };

  // --- precomputed swizzled frag bases (bytes); reads = base + frag*2048 ---
  int aP[2], bP[2];
#pragma unroll
  for (int ks = 0; ks < 2; ++ks) {
    int La = (wm * 64 + (lane & 15)) * 128 + (lane >> 4) * 16 + ks * 64;
    aP[ks] = La ^ ((lane & 7) << 4);
    int Lb = (wn * 32 + (lane & 15)) * 128 + (lane >> 4) * 16 + ks * 64;
    bP[ks] = Lb ^ ((lane & 7) << 4);
  }

  f32x4 acc[4][2];
#pragma unroll
  for (int m = 0; m < 4; ++m)
#pragma unroll
    for (int n = 0; n < 2; ++n) acc[m][n] = (f32x4){0.f, 0.f, 0.f, 0.f};

  // --- prologue: A(0), B(0), A(1); vmcnt(2) forces tile0, leaves A(1) ---
  stageA(0); stageB(0); stageA(1);
  asm volatile("s_waitcnt vmcnt(2)" ::: "memory");
  __builtin_amdgcn_s_barrier();

  for (int t = 0; t < NT; ++t) {
    const char* LA = (const char*)&ldsA[t % 3][0];
    const char* LB = (const char*)&ldsB[t & 1][0];

    bf16x8 a_[2][4], b_[2][2];
#pragma unroll
    for (int ks = 0; ks < 2; ++ks) {
#pragma unroll
      for (int m = 0; m < 4; ++m) a_[ks][m] = *(const bf16x8*)(LA + aP[ks] + m * 2048);
#pragma unroll
      for (int n = 0; n < 2; ++n) b_[ks][n] = *(const bf16x8*)(LB + bP[ks] + n * 2048);
    }
    if (t + 1 < NT) stageB(t + 1);         // older in issue order
    if (t + 2 < NT) stageA(t + 2);
    asm volatile("s_waitcnt lgkmcnt(0)" ::: "memory");
    __builtin_amdgcn_s_setprio(1);
#pragma unroll
    for (int m = 0; m < 4; ++m)
#pragma unroll
      for (int n = 0; n < 2; ++n) {
        acc[m][n] = __builtin_amdgcn_mfma_f32_16x16x32_bf16(a_[0][m], b_[0][n], acc[m][n], 0, 0, 0);
        acc[m][n] = __builtin_amdgcn_mfma_f32_16x16x32_bf16(a_[1][m], b_[1][n], acc[m][n], 0, 0, 0);
      }
    __builtin_amdgcn_s_setprio(0);
    // gate: force tile t+1 (A(t+1)+B(t+1)); leave A(t+2)'s 2 in flight
    if (t < NT - 2)       asm volatile("s_waitcnt vmcnt(2)" ::: "memory");
    else if (t == NT - 2) asm volatile("s_waitcnt vmcnt(0)" ::: "memory");
    __builtin_amdgcn_s_barrier();
  }

  // ---- epilogue: D row = q, col = co; p fixed ----
#pragma unroll
  for (int n = 0; n < 2; ++n) {
    int co = nh * 128 + wn * 32 + n * 16 + (lane & 15);
    float bv = bias[co];
    float* yp = y + (((size_t)(b * 256 + co)) * 128 + p) * 128;
#pragma unroll
    for (int m = 0; m < 4; ++m) {
      int q0 = wm * 64 + m * 16 + ((lane >> 4) << 2);
      f32x4 vv = acc[m][n];
      vv[0] += bv; vv[1] += bv; vv[2] += bv; vv[3] += bv;
      *(f32x4*)(yp + q0) = vv;
    }
  }
}

// ---------------------------------------------------------------------------
extern "C" void kernel_launch(void* const* d_in, const int* in_sizes, int n_in,
                              void* d_out, int out_size, void* d_ws, size_t ws_size,
                              hipStream_t stream) {
  const float* x    = (const float*)d_in[0];
  const float* W    = (const float*)d_in[1];
  const float* bias = (const float*)d_in[2];
  float* y = (float*)d_out;

  const size_t hT_bytes = (size_t)16 * PH * PH * 256 * 2;   // 138,444,800
  const size_t A_bytes  = (size_t)256 * 2304 * 2;           //   1,179,648
  if (ws_size < hT_bytes + A_bytes) return;

  short* hT = (short*)d_ws;
  short* Wp = (short*)((char*)d_ws + hT_bytes);

  wpack<<<(256 * 2304 + 255) / 256, 256, 0, stream>>>(W, Wp);
  dim3 g1(16 * 65, 4);
  fir_up<<<g1, 256, 0, stream>>>(x, hT);
  conv3x3_gemm<<<4096, 512, 0, stream>>>(hT, Wp, bias, y);
}